// Round 1
// baseline (424.702 us; speedup 1.0000x reference)
//
#include <hip/hip_runtime.h>

// waspGridSpatialIntegral: out[:,0] = cumsum_x(in[:,0]), out[:,1] = cumsum_y(in[:,1])
// B=128, W=512, fp32. Memory-bound: 256 MiB in + 256 MiB out.

#define W 512
#define BATCH 128
#define NB1 256  // channel-1 (y-cumsum) blocks, scheduled first

__global__ __launch_bounds__(256) void spatial_integral_kernel(
    const float* __restrict__ in, float* __restrict__ out) {
    const int bid = blockIdx.x;

    if (bid < NB1) {
        // ---- channel 1: cumsum over y (columns). One thread per column. ----
        // block covers 256 consecutive columns of one image's channel 1.
        const int b     = bid >> 1;
        const int xbase = (bid & 1) * 256;
        const int x     = xbase + threadIdx.x;
        const size_t base = (size_t)b * 2 * W * W + (size_t)W * W + (size_t)x;
        const float* ip = in  + base;
        float*       op = out + base;
        float sum = 0.0f;
        for (int y0 = 0; y0 < W; y0 += 8) {
            float v[8];
            #pragma unroll
            for (int j = 0; j < 8; ++j)
                v[j] = ip[(size_t)(y0 + j) * W];      // 8 independent loads in flight
            #pragma unroll
            for (int j = 0; j < 8; ++j) {
                sum += v[j];
                op[(size_t)(y0 + j) * W] = sum;
            }
        }
    } else {
        // ---- channel 0: cumsum over x (rows). One wave per 512-float row. ----
        const int rb   = bid - NB1;
        const int wave = threadIdx.x >> 6;
        const int lane = threadIdx.x & 63;
        const int row  = rb * 4 + wave;        // [0, B*W)
        const int b    = row >> 9;             // row / 512
        const int y    = row & 511;
        const size_t base = (size_t)b * 2 * W * W + (size_t)y * W;  // channel 0
        const float4* ip4 = (const float4*)(in + base);
        float4*       op4 = (float4*)(out + base);

        const float4 a = ip4[lane * 2];
        const float4 c = ip4[lane * 2 + 1];
        float p[8] = {a.x, a.y, a.z, a.w, c.x, c.y, c.z, c.w};
        #pragma unroll
        for (int j = 1; j < 8; ++j) p[j] += p[j - 1];

        // exclusive scan of lane totals across the 64-lane wave
        const float tot = p[7];
        float scan = tot;
        #pragma unroll
        for (int off = 1; off < 64; off <<= 1) {
            const float n = __shfl_up(scan, off, 64);
            if (lane >= off) scan += n;
        }
        const float excl = scan - tot;

        #pragma unroll
        for (int j = 0; j < 8; ++j) p[j] += excl;
        op4[lane * 2]     = make_float4(p[0], p[1], p[2], p[3]);
        op4[lane * 2 + 1] = make_float4(p[4], p[5], p[6], p[7]);
    }
}

extern "C" void kernel_launch(void* const* d_in, const int* in_sizes, int n_in,
                              void* d_out, int out_size, void* d_ws, size_t ws_size,
                              hipStream_t stream) {
    const float* in = (const float*)d_in[0];
    float* out = (float*)d_out;
    // ch1 blocks first (long-running), then B*W/4 = 16384 ch0 row-blocks.
    const int nblocks = NB1 + (BATCH * W) / 4;
    spatial_integral_kernel<<<dim3(nblocks), dim3(256), 0, stream>>>(in, out);
}